// Round 2
// baseline (234.970 us; speedup 1.0000x reference)
//
#include <hip/hip_runtime.h>
#include <hip/hip_cooperative_groups.h>

namespace cg = cooperative_groups;

// TT-linear: y = x[16384,784] @ W[784,512] + bias; out = softmax(relu(y), axis=1)
// Single fused cooperative kernel, grid 256 x 512 (1 block/CU, co-resident).
// Phase 0: waves 0-3 stage this block's A-tile (x -> bf16 -> LDS, frag order)
//          while waves 4-7 of blocks 0-224 build W (bf16, MFMA B-fragment
//          layout) into ws. Prep hides under the HBM A-stage stream.
// threadfence (cross-XCD L2 writeback) + grid.sync(), then:
// Phase 1: 25-tile K-loop, B dist-2 register pipeline from L2, A dist-1 from
//          LDS, 16 MFMA/iter/wave, fused bias+relu+softmax epilogue.
//
// ws: [0, 819200) Wp bf16, idx = ((tn*25+tk)*64 + lane)*8 + j
//     = W[k=tk*32+quad*8+j][n=tn*16+lid]   (lane = quad*16+lid)

typedef __attribute__((ext_vector_type(8))) short short8;
typedef __attribute__((ext_vector_type(4))) float floatx4;

__device__ __forceinline__ unsigned int pack2_bf16(float a, float b) {
    unsigned int ua = __float_as_uint(a);
    unsigned int ub = __float_as_uint(b);
    return ((ub + 0x8000u) & 0xFFFF0000u) | ((ua + 0x8000u) >> 16);
}

__device__ __forceinline__ short f32_to_bf16_rne(float v) {
    unsigned int u = __float_as_uint(v);
    return (short)(((u + 0x7FFFu + ((u >> 16) & 1)) >> 16) & 0xFFFF);
}

__global__ __launch_bounds__(512, 2) void tt_fused(
    const float* __restrict__ x,
    const float* __restrict__ c1, const float* __restrict__ c2,
    const float* __restrict__ c3, const float* __restrict__ c4,
    const float* __restrict__ bias,
    short* __restrict__ wp,
    float* __restrict__ out)
{
    __shared__ __align__(16) short s_a[6400 * 8];   // 102.4 KB: 25 tk x 256 chunks
    __shared__ float part[8][64];                   // 2 KB
    __shared__ float t12s[320];                     // prep: [pq(16)][s(20)]
    __shared__ float t123s[7 * 256];                // prep: [k3][pql][t]
    __shared__ float c4s[256];                      // prep: [t][l][f4]

    const int tid  = threadIdx.x;
    const int blk  = blockIdx.x;
    const int w    = tid >> 6;
    const int lane = tid & 63;
    const int quad = lane >> 4;
    const int lid  = lane & 15;
    const int m_base = blk * 64;
    const bool stager = (w < 4);
    const int tp = tid & 255;          // stage: tid (0..255); prep: tid-256

    // prep geometry (blocks 0..223)
    const int ij    = blk >> 3;
    const int strip = blk & 7;
    const int i  = ij >> 2, j2 = ij & 3;
    const int p  = strip >> 1;
    const int qh = strip & 1;

    // ================= phase 0, segment 1 =================
    if (stager) {
        #pragma unroll
        for (int it = 0; it < 9; ++it) {
            const int a   = tp + it * 256;
            const int row = ((a >> 6) & 3) * 16 + (a & 15);
            const int kc  = ((a >> 8) * 4 + ((a >> 4) & 3)) * 8;
            floatx4 v0 = {0.f,0.f,0.f,0.f}, v1 = {0.f,0.f,0.f,0.f};
            if (kc < 784) {
                const floatx4* pp = (const floatx4*)(x + (size_t)(m_base + row) * 784 + kc);
                v0 = pp[0]; v1 = pp[1];
            }
            union { short8 s; unsigned int u[4]; } af;
            af.u[0] = pack2_bf16(v0.x, v0.y);
            af.u[1] = pack2_bf16(v0.z, v0.w);
            af.u[2] = pack2_bf16(v1.x, v1.y);
            af.u[3] = pack2_bf16(v1.z, v1.w);
            *(short8*)&s_a[a * 8] = af.s;
        }
    } else if (blk < 224) {
        c4s[tp] = c4[tp];
        for (int e = tp; e < 320; e += 256) {
            int s = e % 20, pq = e / 20;
            int pp_ = pq >> 2, q = pq & 3;
            float acc = 0.f;
            #pragma unroll
            for (int r = 0; r < 20; ++r)
                acc += c1[i * 80 + pp_ * 20 + r] * c2[r * 320 + j2 * 80 + q * 20 + s];
            t12s[e] = acc;
        }
    }
    __syncthreads();

    // ================= phase 0, segment 2 =================
    if (stager) {
        #pragma unroll
        for (int it = 9; it < 17; ++it) {
            const int a   = tp + it * 256;
            const int row = ((a >> 6) & 3) * 16 + (a & 15);
            const int kc  = ((a >> 8) * 4 + ((a >> 4) & 3)) * 8;
            floatx4 v0 = {0.f,0.f,0.f,0.f}, v1 = {0.f,0.f,0.f,0.f};
            if (kc < 784) {
                const floatx4* pp = (const floatx4*)(x + (size_t)(m_base + row) * 784 + kc);
                v0 = pp[0]; v1 = pp[1];
            }
            union { short8 s; unsigned int u[4]; } af;
            af.u[0] = pack2_bf16(v0.x, v0.y);
            af.u[1] = pack2_bf16(v0.z, v0.w);
            af.u[2] = pack2_bf16(v1.x, v1.y);
            af.u[3] = pack2_bf16(v1.z, v1.w);
            *(short8*)&s_a[a * 8] = af.s;
        }
    } else if (blk < 224) {
        for (int e = tp; e < 1792; e += 256) {          // exactly 7 iters
            int k3 = e >> 8, li = e & 255;
            int t = li & 15, pql = li >> 4;
            int qloc = pql >> 3, e3 = pql & 7;
            int q = 2 * qh + qloc;
            float acc = 0.f;
            const float* tpt = t12s + (p * 4 + q) * 20;
            const float* cp  = c3 + k3 * 128 + e3 * 16 + t;
            #pragma unroll
            for (int s = 0; s < 20; ++s) acc += tpt[s] * cp[s * 896];
            t123s[e] = acc;
        }
    }
    __syncthreads();

    // ================= phase 0, segment 3 =================
    if (stager) {
        #pragma unroll
        for (int it = 17; it < 25; ++it) {
            const int a   = tp + it * 256;
            const int row = ((a >> 6) & 3) * 16 + (a & 15);
            const int kc  = ((a >> 8) * 4 + ((a >> 4) & 3)) * 8;
            floatx4 v0 = {0.f,0.f,0.f,0.f}, v1 = {0.f,0.f,0.f,0.f};
            if (kc < 784) {
                const floatx4* pp = (const floatx4*)(x + (size_t)(m_base + row) * 784 + kc);
                v0 = pp[0]; v1 = pp[1];
            }
            union { short8 s; unsigned int u[4]; } af;
            af.u[0] = pack2_bf16(v0.x, v0.y);
            af.u[1] = pack2_bf16(v0.z, v0.w);
            af.u[2] = pack2_bf16(v1.x, v1.y);
            af.u[3] = pack2_bf16(v1.z, v1.w);
            *(short8*)&s_a[a * 8] = af.s;
        }
    } else if (blk < 224) {
        for (int e = tp; e < 1792; e += 256) {          // exactly 7 iters
            int kl = e >> 6, nl = e & 63;
            int k = ij * 28 + kl;
            int n = strip * 64 + nl;
            int k3 = kl >> 2, l = kl & 3;
            int f4 = n & 3, e3 = (n >> 2) & 7;
            int pql = ((n >> 5) & 1) * 8 + e3;
            const float* tpt = t123s + k3 * 256 + pql * 16;
            const float* cq  = c4s + l * 4 + f4;
            float a = 0.f;
            #pragma unroll
            for (int t = 0; t < 16; ++t) a += tpt[t] * cq[t * 16];
            int tk = k >> 5, q4 = (k >> 3) & 3, j = k & 7;
            int tn = n >> 4, nlid = n & 15;
            wp[(((tn * 25 + tk) * 64 + q4 * 16 + nlid) << 3) + j] = f32_to_bf16_rne(a);
        }
    } else if (blk == 224) {
        for (int e = tp; e < 8192; e += 256) {           // zero wp for k in [784,800)
            int j   = e & 7;
            int nlid = (e >> 3) & 15;
            int q2  = (e >> 7) & 1;
            int tn  = e >> 8;
            wp[(((tn * 25 + 24) * 64 + (2 + q2) * 16 + nlid) << 3) + j] = 0;
        }
    }

    // cross-XCD visibility of wp: agent-scope release (waitcnt + L2 writeback)
    __threadfence();
    cg::this_grid().sync();

    // ================= phase 1: K-loop + epilogue =================
    const short* wpw = wp + ((size_t)(w * 4) * 25 * 64 + lane) * 8;   // tn = w*4 + nt

    short8 b_f[3][4];
    #pragma unroll
    for (int nt = 0; nt < 4; ++nt) {
        b_f[0][nt] = *(const short8*)(wpw + (size_t)(nt * 25 + 0) * 64 * 8);
        b_f[1][nt] = *(const short8*)(wpw + (size_t)(nt * 25 + 1) * 64 * 8);
    }

    const short* sa = s_a + lane * 8;

    floatx4 acc[4][4];
    #pragma unroll
    for (int mt = 0; mt < 4; ++mt)
        #pragma unroll
        for (int nt = 0; nt < 4; ++nt)
            acc[mt][nt] = floatx4{0.f, 0.f, 0.f, 0.f};

    short8 a_f[2][4];
    #pragma unroll
    for (int mt = 0; mt < 4; ++mt)
        a_f[0][mt] = *(const short8*)(sa + (size_t)(mt * 64) * 8);

    #pragma unroll
    for (int tk = 0; tk < 25; ++tk) {
        if (tk + 2 < 25) {                            // B prefetch, distance 2
            #pragma unroll
            for (int nt = 0; nt < 4; ++nt)
                b_f[(tk + 2) % 3][nt] = *(const short8*)(wpw + (size_t)(nt * 25 + tk + 2) * 64 * 8);
        }
        if (tk + 1 < 25) {                            // A prefetch, distance 1 (LDS)
            const short* sa2 = sa + (size_t)(tk + 1) * 256 * 8;
            #pragma unroll
            for (int mt = 0; mt < 4; ++mt)
                a_f[(tk + 1) & 1][mt] = *(const short8*)(sa2 + (size_t)(mt * 64) * 8);
        }
        #pragma unroll
        for (int nt = 0; nt < 4; ++nt)
            #pragma unroll
            for (int mt = 0; mt < 4; ++mt)
                acc[mt][nt] = __builtin_amdgcn_mfma_f32_16x16x32_bf16(a_f[tk & 1][mt], b_f[tk % 3][nt], acc[mt][nt], 0, 0, 0);
    }

    // ---- epilogue: bias + relu + exp, row sums across 8 waves, scale, store ----
    float bias_v[4];
    #pragma unroll
    for (int nt = 0; nt < 4; ++nt)
        bias_v[nt] = bias[w * 64 + nt * 16 + lid];

    #pragma unroll
    for (int mt = 0; mt < 4; ++mt) {
        #pragma unroll
        for (int reg = 0; reg < 4; ++reg) {
            float s = 0.f;
            #pragma unroll
            for (int nt = 0; nt < 4; ++nt) {
                float v = acc[mt][nt][reg] + bias_v[nt];
                v = fmaxf(v, 0.f);
                float e = __expf(v);
                acc[mt][nt][reg] = e;
                s += e;
            }
            s += __shfl_xor(s, 1, 64);
            s += __shfl_xor(s, 2, 64);
            s += __shfl_xor(s, 4, 64);
            s += __shfl_xor(s, 8, 64);
            if (lid == 0) part[w][mt * 16 + quad * 4 + reg] = s;
        }
    }
    __syncthreads();

    #pragma unroll
    for (int mt = 0; mt < 4; ++mt) {
        #pragma unroll
        for (int reg = 0; reg < 4; ++reg) {
            const int row = mt * 16 + quad * 4 + reg;
            float tot = 0.f;
            #pragma unroll
            for (int ww = 0; ww < 8; ++ww) tot += part[ww][row];
            const float inv = 1.0f / tot;
            #pragma unroll
            for (int nt = 0; nt < 4; ++nt)
                out[(size_t)(m_base + row) * 512 + w * 64 + nt * 16 + lid] = acc[mt][nt][reg] * inv;
        }
    }
}

extern "C" void kernel_launch(void* const* d_in, const int* in_sizes, int n_in,
                              void* d_out, int out_size, void* d_ws, size_t ws_size,
                              hipStream_t stream) {
    const float* x    = (const float*)d_in[0];
    const float* c1   = (const float*)d_in[1];
    const float* c2   = (const float*)d_in[2];
    const float* c3   = (const float*)d_in[3];
    const float* c4   = (const float*)d_in[4];
    const float* bias = (const float*)d_in[5];
    float* out = (float*)d_out;
    short* wpb = (short*)d_ws;

    void* args[] = {(void*)&x, (void*)&c1, (void*)&c2, (void*)&c3,
                    (void*)&c4, (void*)&bias, (void*)&wpb, (void*)&out};
    hipLaunchCooperativeKernel(reinterpret_cast<void*>(&tt_fused),
                               dim3(256), dim3(512), args, 0, stream);
}

// Round 3
// 124.811 us; speedup vs baseline: 1.8826x; 1.8826x over previous
//
#include <hip/hip_runtime.h>

// TT-linear: y = x[16384,784] @ W[784,512] + bias; out = softmax(relu(y), axis=1)
// prep_all: 449 blocks build W (bf16, MFMA B-fragment layout) from TT cores.
//           Block b<448: ij = b>>4 (28 k-values), sub = b&15 -> (p,q), 32 n-values.
//           Block 448: zero-fill K-pad rows k in [784,800).
// tt_gemm : M=64 tile (grid 256, 1 block/CU). A staged in LDS (bf16, frag
//           order) with T14 async split: phase-B x-loads issued into held
//           registers before the first barrier, written to LDS after the
//           phase-A K-loop. B dist-2 register pipeline from L2,
//           16 MFMA/iter/wave, fused bias+relu+softmax epilogue.
//
// ws: [0, 819200) Wp bf16, idx = ((tn*25+tk)*64 + lane)*8 + j
//     = W[k=tk*32+quad*8+j][n=tn*16+lid]   (lane = quad*16+lid)
//     n = p*128 + q*32 + e3*4 + f4

typedef __attribute__((ext_vector_type(8))) short short8;
typedef __attribute__((ext_vector_type(4))) float floatx4;

__device__ __forceinline__ unsigned int pack2_bf16(float a, float b) {
    unsigned int ua = __float_as_uint(a);
    unsigned int ub = __float_as_uint(b);
    return ((ub + 0x8000u) & 0xFFFF0000u) | ((ua + 0x8000u) >> 16);
}

__device__ __forceinline__ short f32_to_bf16_rne(float v) {
    unsigned int u = __float_as_uint(v);
    return (short)(((u + 0x7FFFu + ((u >> 16) & 1)) >> 16) & 0xFFFF);
}

// ---------- prep: t12 row -> t123 slice -> wp slice, 449 blocks x 256 ----------
__global__ void prep_all(const float* __restrict__ c1, const float* __restrict__ c2,
                         const float* __restrict__ c3, const float* __restrict__ c4,
                         short* __restrict__ wp) {
    const int tid = threadIdx.x;
    const int blk = blockIdx.x;
    if (blk == 448) {                      // zero wp for k in [784,800)
        for (int e = tid; e < 8192; e += 256) {
            int j   = e & 7;
            int lid = (e >> 3) & 15;
            int q2  = (e >> 7) & 1;
            int tn  = e >> 8;
            wp[(((tn * 25 + 24) * 64 + (2 + q2) * 16 + lid) << 3) + j] = 0;
        }
        return;
    }
    __shared__ float t12s[20];             // [s] for this (p,q)
    __shared__ float t123s[7 * 128];       // [k3(7)][e3(8)][t(16)]
    __shared__ float c4s[256];             // [t(16)][l(4)][f4(4)]

    const int ij  = blk >> 4;
    const int sub = blk & 15;
    const int i  = ij >> 2, j2 = ij & 3;
    const int p  = sub >> 2;
    const int q  = sub & 3;

    if (tid < 256) c4s[tid] = c4[tid];
    if (tid < 20) {
        const int s = tid;
        float acc = 0.f;
        #pragma unroll
        for (int r = 0; r < 20; ++r)
            acc += c1[i * 80 + p * 20 + r] * c2[r * 320 + j2 * 80 + q * 20 + s];
        t12s[s] = acc;
    }
    __syncthreads();

    for (int e = tid; e < 896; e += 256) {           // 3.5 iters
        int k3 = e >> 7, li = e & 127;
        int t = li & 15, e3 = li >> 4;
        float acc = 0.f;
        const float* cp = c3 + k3 * 128 + e3 * 16 + t;
        #pragma unroll
        for (int s = 0; s < 20; ++s) acc += t12s[s] * cp[s * 896];
        t123s[e] = acc;
    }
    __syncthreads();

    for (int e = tid; e < 896; e += 256) {           // 3.5 iters
        int kl = e >> 5, nl = e & 31;                // kl in [0,28), nl in [0,32)
        int k = ij * 28 + kl;
        int n = p * 128 + q * 32 + nl;
        int k3 = kl >> 2, l = kl & 3;
        int f4 = nl & 3, e3 = nl >> 2;
        const float* tp = t123s + k3 * 128 + e3 * 16;
        const float* cq = c4s + l * 4 + f4;
        float a = 0.f;
        #pragma unroll
        for (int t = 0; t < 16; ++t) a += tp[t] * cq[t * 16];
        int tk = k >> 5, quad = (k >> 3) & 3, j = k & 7;
        int tn = n >> 4, lid = n & 15;
        wp[(((tn * 25 + tk) * 64 + quad * 16 + lid) << 3) + j] = f32_to_bf16_rne(a);
    }
}

// ---------- main GEMM + bias + relu + softmax ----------
// grid 256 (64 rows each), block 512 = 8 waves; wave w owns cols [w*64, w*64+64).
// A in LDS (bf16, chunk = tk*256 + mt*64 + lane), 25 K-tiles total.
// Phase split at tk=18: phase-B chunks (tk 18..24) pre-loaded into registers
// before the first barrier; their HBM latency hides under the phase-A K-loop.
__global__ __launch_bounds__(512, 2) void tt_gemm(const float* __restrict__ x,
                                                  const short* __restrict__ wp,
                                                  const float* __restrict__ bias,
                                                  float* __restrict__ out) {
    __shared__ __align__(16) short s_a[6400 * 8];   // 102.4 KB: 25 tk x 256 chunks
    __shared__ float part[8][64];

    const int tid  = threadIdx.x;
    const int w    = tid >> 6;
    const int lane = tid & 63;
    const int quad = lane >> 4;
    const int lid  = lane & 15;
    const int m_base = blockIdx.x * 64;

    const short* wpw = wp + ((size_t)(w * 4) * 25 * 64 + lane) * 8;   // tn = w*4 + nt

    // issue B tiles 0 and 1 first — they drain alongside the staging loads
    short8 b_f[3][4];
    #pragma unroll
    for (int nt = 0; nt < 4; ++nt) {
        b_f[0][nt] = *(const short8*)(wpw + (size_t)(nt * 25 + 0) * 64 * 8);
        b_f[1][nt] = *(const short8*)(wpw + (size_t)(nt * 25 + 1) * 64 * 8);
    }

    // ---- T14: issue phase-B x-loads (chunks 4608..6399, tk 18..24) now ----
    floatx4 h0[4], h1[4];
    #pragma unroll
    for (int i = 0; i < 4; ++i) {
        h0[i] = floatx4{0.f, 0.f, 0.f, 0.f};
        h1[i] = floatx4{0.f, 0.f, 0.f, 0.f};
        const int c = 4608 + tid + i * 512;
        if (c < 6400) {
            const int row = ((c >> 6) & 3) * 16 + (c & 15);
            const int kc  = ((c >> 8) * 4 + ((c >> 4) & 3)) * 8;
            if (kc < 784) {
                const floatx4* pp = (const floatx4*)(x + (size_t)(m_base + row) * 784 + kc);
                h0[i] = pp[0]; h1[i] = pp[1];
            }
        }
    }

    // ---- stage phase A: chunks 0..4607 (tk 0..17), kc always < 784 ----
    #pragma unroll
    for (int it = 0; it < 9; ++it) {
        const int a   = tid + it * 512;
        const int row = ((a >> 6) & 3) * 16 + (a & 15);
        const int kc  = ((a >> 8) * 4 + ((a >> 4) & 3)) * 8;
        const floatx4* pp = (const floatx4*)(x + (size_t)(m_base + row) * 784 + kc);
        floatx4 v0 = pp[0], v1 = pp[1];
        union { short8 s; unsigned int u[4]; } af;
        af.u[0] = pack2_bf16(v0.x, v0.y);
        af.u[1] = pack2_bf16(v0.z, v0.w);
        af.u[2] = pack2_bf16(v1.x, v1.y);
        af.u[3] = pack2_bf16(v1.z, v1.w);
        *(short8*)&s_a[a * 8] = af.s;
    }
    __syncthreads();

    const short* sa = s_a + lane * 8;

    floatx4 acc[4][4];
    #pragma unroll
    for (int mt = 0; mt < 4; ++mt)
        #pragma unroll
        for (int nt = 0; nt < 4; ++nt)
            acc[mt][nt] = floatx4{0.f, 0.f, 0.f, 0.f};

    short8 a_f[2][4];
    #pragma unroll
    for (int mt = 0; mt < 4; ++mt)
        a_f[0][mt] = *(const short8*)(sa + (size_t)(mt * 64) * 8);

    // ---- K-loop phase A: tk 0..17 ----
    #pragma unroll
    for (int tk = 0; tk < 18; ++tk) {
        #pragma unroll
        for (int nt = 0; nt < 4; ++nt)                // B prefetch, distance 2
            b_f[(tk + 2) % 3][nt] = *(const short8*)(wpw + (size_t)(nt * 25 + tk + 2) * 64 * 8);
        if (tk + 1 < 18) {                            // A prefetch, distance 1 (LDS)
            const short* sa2 = sa + (size_t)(tk + 1) * 256 * 8;
            #pragma unroll
            for (int mt = 0; mt < 4; ++mt)
                a_f[(tk + 1) & 1][mt] = *(const short8*)(sa2 + (size_t)(mt * 64) * 8);
        }
        #pragma unroll
        for (int nt = 0; nt < 4; ++nt)
            #pragma unroll
            for (int mt = 0; mt < 4; ++mt)
                acc[mt][nt] = __builtin_amdgcn_mfma_f32_16x16x32_bf16(a_f[tk & 1][mt], b_f[tk % 3][nt], acc[mt][nt], 0, 0, 0);
    }

    // ---- write phase-B chunks from held registers (loads long since landed) ----
    #pragma unroll
    for (int i = 0; i < 4; ++i) {
        const int c = 4608 + tid + i * 512;
        if (c < 6400) {
            union { short8 s; unsigned int u[4]; } af;
            af.u[0] = pack2_bf16(h0[i].x, h0[i].y);
            af.u[1] = pack2_bf16(h0[i].z, h0[i].w);
            af.u[2] = pack2_bf16(h1[i].x, h1[i].y);
            af.u[3] = pack2_bf16(h1[i].z, h1[i].w);
            *(short8*)&s_a[c * 8] = af.s;
        }
    }
    __syncthreads();

    // reload A pipeline for tk=18 (even -> slot 0)
    #pragma unroll
    for (int mt = 0; mt < 4; ++mt)
        a_f[0][mt] = *(const short8*)(sa + ((size_t)18 * 256 + mt * 64) * 8);

    // ---- K-loop phase B: tk 18..24 ----
    #pragma unroll
    for (int tk = 18; tk < 25; ++tk) {
        if (tk + 2 < 25) {                            // B prefetch, distance 2
            #pragma unroll
            for (int nt = 0; nt < 4; ++nt)
                b_f[(tk + 2) % 3][nt] = *(const short8*)(wpw + (size_t)(nt * 25 + tk + 2) * 64 * 8);
        }
        if (tk + 1 < 25) {                            // A prefetch, distance 1 (LDS)
            const short* sa2 = sa + (size_t)(tk + 1) * 256 * 8;
            #pragma unroll
            for (int mt = 0; mt < 4; ++mt)
                a_f[(tk + 1) & 1][mt] = *(const short8*)(sa2 + (size_t)(mt * 64) * 8);
        }
        #pragma unroll
        for (int nt = 0; nt < 4; ++nt)
            #pragma unroll
            for (int mt = 0; mt < 4; ++mt)
                acc[mt][nt] = __builtin_amdgcn_mfma_f32_16x16x32_bf16(a_f[tk & 1][mt], b_f[tk % 3][nt], acc[mt][nt], 0, 0, 0);
    }

    // ---- epilogue: bias + relu + exp, row sums across 8 waves, scale, store ----
    float bias_v[4];
    #pragma unroll
    for (int nt = 0; nt < 4; ++nt)
        bias_v[nt] = bias[w * 64 + nt * 16 + lid];

    #pragma unroll
    for (int mt = 0; mt < 4; ++mt) {
        #pragma unroll
        for (int reg = 0; reg < 4; ++reg) {
            float s = 0.f;
            #pragma unroll
            for (int nt = 0; nt < 4; ++nt) {
                float v = acc[mt][nt][reg] + bias_v[nt];
                v = fmaxf(v, 0.f);
                float e = __expf(v);
                acc[mt][nt][reg] = e;
                s += e;
            }
            s += __shfl_xor(s, 1, 64);
            s += __shfl_xor(s, 2, 64);
            s += __shfl_xor(s, 4, 64);
            s += __shfl_xor(s, 8, 64);
            if (lid == 0) part[w][mt * 16 + quad * 4 + reg] = s;
        }
    }
    __syncthreads();

    #pragma unroll
    for (int mt = 0; mt < 4; ++mt) {
        #pragma unroll
        for (int reg = 0; reg < 4; ++reg) {
            const int row = mt * 16 + quad * 4 + reg;
            float tot = 0.f;
            #pragma unroll
            for (int ww = 0; ww < 8; ++ww) tot += part[ww][row];
            const float inv = 1.0f / tot;
            #pragma unroll
            for (int nt = 0; nt < 4; ++nt)
                out[(size_t)(m_base + row) * 512 + w * 64 + nt * 16 + lid] = acc[mt][nt][reg] * inv;
        }
    }
}

extern "C" void kernel_launch(void* const* d_in, const int* in_sizes, int n_in,
                              void* d_out, int out_size, void* d_ws, size_t ws_size,
                              hipStream_t stream) {
    const float* x    = (const float*)d_in[0];
    const float* c1   = (const float*)d_in[1];
    const float* c2   = (const float*)d_in[2];
    const float* c3   = (const float*)d_in[3];
    const float* c4   = (const float*)d_in[4];
    const float* bias = (const float*)d_in[5];
    float* out = (float*)d_out;
    short* wpb = (short*)d_ws;

    prep_all<<<449, 256, 0, stream>>>(c1, c2, c3, c4, wpb);
    tt_gemm <<<256, 512, 0, stream>>>(x, wpb, bias, out);
}